// Round 3
// baseline (1880.185 us; speedup 1.0000x reference)
//
#include <hip/hip_runtime.h>

// log-ODE Neural CDE. B=32 chains, 32 windows, Heun step = 2 vector-field
// evals per window. DTYPE-ADAPTIVE: detects bf16 vs fp32 tensors at runtime
// (scans W3 for impossible bf16 bit patterns). fp32 internal math either way.
// One 256-thread block per batch element (chain is sequential). No d_ws.
#define NBATCH 32
#define LPATH  513
#define DIM    8
#define HID    64
#define WLEN   16
#define NWIN   32
#define NOUT   4
#define WID    128
#define LSIG   36

typedef unsigned int u32;
typedef unsigned short u16;

__device__ __forceinline__ float bf2f(u16 h){ return __uint_as_float(((u32)h)<<16); }
__device__ __forceinline__ float plo(u32 u){ return __uint_as_float(u<<16); }
__device__ __forceinline__ float phi(u32 u){ return __uint_as_float(u & 0xffff0000u); }
__device__ __forceinline__ u16 f2bf(float f){
  u32 u = __float_as_uint(f);
  u32 r = (u + 0x7fffu + ((u>>16)&1u)) >> 16;
  return (u16)r;
}
__device__ __forceinline__ float tanh_fast(float x){
  float e = __expf(2.f*x);
  return 1.f - 2.f/(e+1.f);   // saturates to +/-1, no NaN for finite x
}

// ---- dtype-generic accessors (isbf is block-uniform) ----
__device__ __forceinline__ float gelem(const void* p, int i, bool isbf){
  return isbf ? bf2f(((const u16*)p)[i]) : ((const float*)p)[i];
}
// elements 2i, 2i+1 packed as bf16 pair (fp32 path: RNE-rounded)
__device__ __forceinline__ u32 gpair(const void* p, int i, bool isbf){
  if (isbf) return ((const u32*)p)[i];
  const float2 f = ((const float2*)p)[i];
  return (u32)f2bf(f.x) | ((u32)f2bf(f.y) << 16);
}
// elements 8*i8 .. 8*i8+7 as fp32 (exact in both dtypes)
__device__ __forceinline__ void gload8(const void* p, int i8, bool isbf, float* o){
  if (isbf){
    const uint4 v = ((const uint4*)p)[i8];
    o[0]=plo(v.x); o[1]=phi(v.x); o[2]=plo(v.y); o[3]=phi(v.y);
    o[4]=plo(v.z); o[5]=phi(v.z); o[6]=plo(v.w); o[7]=phi(v.w);
  } else {
    const float4 a = ((const float4*)p)[2*i8];
    const float4 b = ((const float4*)p)[2*i8+1];
    o[0]=a.x; o[1]=a.y; o[2]=a.z; o[3]=a.w;
    o[4]=b.x; o[5]=b.y; o[6]=b.z; o[7]=b.w;
  }
}
// W3 row `row`, cols 8l..8l+7 as fp32
__device__ __forceinline__ void w3chunk(const void* W3, int row, int l, bool isbf, float* w8){
  if (isbf){
    const uint4 v = ((const uint4*)W3)[row*16 + l];
    w8[0]=plo(v.x); w8[1]=phi(v.x); w8[2]=plo(v.y); w8[3]=phi(v.y);
    w8[4]=plo(v.z); w8[5]=phi(v.z); w8[6]=plo(v.w); w8[7]=phi(v.w);
  } else {
    const float4 a = ((const float4*)W3)[row*32 + 2*l];
    const float4 b = ((const float4*)W3)[row*32 + 2*l + 1];
    w8[0]=a.x; w8[1]=a.y; w8[2]=a.z; w8[3]=a.w;
    w8[4]=b.x; w8[5]=b.y; w8[6]=b.z; w8[7]=b.w;
  }
}

extern "C" __global__ __launch_bounds__(256)
void cde_kernel(const void* __restrict__ cv,
                const void* __restrict__ Wi1g, const void* __restrict__ bi1g,
                const void* __restrict__ Wi2g, const void* __restrict__ bi2g,
                const void* __restrict__ W1g,  const void* __restrict__ b1g,
                const void* __restrict__ W2g,  const void* __restrict__ b2g,
                const void* __restrict__ W3g,  const void* __restrict__ b3g,
                const void* __restrict__ Wrg,  const void* __restrict__ brg,
                const void* __restrict__ shg,
                void* __restrict__ outp)
{
  // ---- LDS (~59 KB, under 64 KB static limit) ----
  __shared__ u32  sW2p[64*128];            // W2 packed col-pairs, [cp][r]
  __shared__ float sG[NWIN*LSIG];          // all window log-signatures
  __shared__ __align__(16) float sF [512]; // f = tanh(W3 h2 + b3)
  __shared__ float sCon[512];              // per-row contributions to k
  __shared__ __align__(16) float sD1[WID*8];  // [row][dir]
  __shared__ __align__(16) float sD2T[8*WID]; // [dir][row]
  __shared__ __align__(16) float sU [8*HID];  // folded JVP directions [j][b]
  __shared__ __align__(16) float sH1[WID];
  __shared__ __align__(16) float sH2[WID];
  __shared__ float sDp1[WID], sDp2[WID];
  __shared__ __align__(16) float sY [HID];
  __shared__ __align__(16) float sYm[HID];
  __shared__ float sK1[HID], sK2[HID];
  __shared__ float sB1[WID], sB2[WID], sB3[512];
  __shared__ float sC[64];                 // signed bracket coeffs C[j*8+i]
  __shared__ float sWr[NOUT*HID];
  __shared__ float sBr[NOUT];
  __shared__ float sShift;
  __shared__ float sLw[HID];
  __shared__ int  sIsF32;

  const int t = threadIdx.x;
  const int b = blockIdx.x;

  // ---- dtype detection: scan W3's first 32768 u32 words. If any bf16-half
  // has exponent >= 130 (|v|>=8; real weights < 0.1), data must be fp32.
  if (t == 0) sIsF32 = 0;
  __syncthreads();
  {
    const u32* w3u = (const u32*)W3g;
    int bad = 0;
    for (int i = t; i < 32768; i += 256){
      u32 w = w3u[i];
      u32 e0 = (w >> 7)  & 0xFFu;
      u32 e1 = (w >> 23) & 0xFFu;
      if (e0 >= 130u || e1 >= 130u) bad = 1;
    }
    if (bad) sIsF32 = 1;        // benign race: all writers store 1
  }
  __syncthreads();
  const bool isbf = (sIsF32 == 0);

  // ---- init: biases, readout weights (exact, native dtype) ----
  if (t < WID){ sB1[t]=gelem(b1g,t,isbf); sB2[t]=gelem(b2g,t,isbf); }
  sB3[t]     = gelem(b3g, t,     isbf);
  sB3[t+256] = gelem(b3g, t+256, isbf);
  sWr[t]     = gelem(Wrg, t,     isbf);
  if (t < NOUT) sBr[t] = gelem(brg, t, isbf);
  if (t == 0)   sShift = gelem(shg, 0, isbf);

  // ---- pack W2 into LDS: sW2p[cp*128+r] = pair (W2[r][2cp], W2[r][2cp+1]) ----
  for (int j = t; j < 64*128; j += 256){
    int r = j >> 6, cp = j & 63;
    sW2p[cp*128 + r] = gpair(W2g, r*64 + cp, isbf);
  }

  // ---- depth-2 Lyndon log-signatures, one window per thread (t<32) ----
  if (t < NWIN){
    const int base8 = b*LPATH + t*WLEN;     // time-step index (8-elem units)
    float cur[8], pre[8], acc[8], lv[28];
    gload8(cv, base8, isbf, cur);
    #pragma unroll
    for (int d=0; d<8; d++){ pre[d]=0.f; acc[d]=0.f; }
    #pragma unroll
    for (int p=0; p<28; p++) lv[p]=0.f;
    for (int w=1; w<=WLEN; w++){
      float nxt[8], inc[8];
      gload8(cv, base8 + w, isbf, nxt);
      #pragma unroll
      for (int d=0; d<8; d++) inc[d] = nxt[d]-cur[d];
      int p=0;
      #pragma unroll
      for (int i=0; i<8; i++)
        #pragma unroll
        for (int j=i+1; j<8; j++){ lv[p] += pre[i]*inc[j] - pre[j]*inc[i]; p++; }
      #pragma unroll
      for (int d=0; d<8; d++){ acc[d]+=inc[d]; pre[d]+=inc[d]; cur[d]=nxt[d]; }
    }
    float* gd = &sG[t*LSIG];
    #pragma unroll
    for (int d=0; d<8; d++) gd[d] = acc[d];
    #pragma unroll
    for (int p=0; p<28; p++) gd[8+p] = 0.5f*lv[p];
  }

  // ---- y0 = Wi2 @ lipswish(Wi1 @ x0 + bi1) + bi2 ----
  if (t < HID){
    float x0[8];
    gload8(cv, b*LPATH, isbf, x0);
    float z = gelem(bi1g, t, isbf);
    #pragma unroll
    for (int d=0; d<8; d++) z += gelem(Wi1g, t*8+d, isbf) * x0[d];
    float s = 1.f/(1.f+__expf(-z));
    sLw[t] = 0.909f*z*s;
  }
  __syncthreads();
  if (t < HID){
    float z = gelem(bi2g, t, isbf);
    #pragma unroll 8
    for (int k=0; k<64; k++) z += gelem(Wi2g, t*64+k, isbf) * sLw[k];
    sY[t] = z;
  }
  __syncthreads();
  if (t < NOUT){
    float z = sBr[t] + sShift;
    #pragma unroll 8
    for (int a=0; a<64; a++) z += sWr[t*64+a]*sY[a];
    int idx = (b*33 + 0)*4 + t;
    if (isbf) ((u16*)outp)[idx] = f2bf(z); else ((float*)outp)[idx] = z;
  }

  // ---- per-thread W1 row registers (row t&127, packed bf16 pairs) ----
  u32 w1p[32];
  {
    int rw = t & 127;
    #pragma unroll
    for (int k=0; k<32; k++) w1p[k] = gpair(W1g, rw*32 + k, isbf);
  }

  const float* gcur = sG;

  // One vector-field eval: yin -> kout (= dt*k = M(y) @ logsig)
  auto EVAL = [&](const float* yin, float* kout){
    __syncthreads();                              // yin, sC ready
    // ph1: z1 = W1@y + b1 ; h1 = lipswish, Dp1 = lipswish'
    if (t < WID){
      float z = sB1[t];
      const float2* y2 = (const float2*)yin;
      #pragma unroll
      for (int k=0; k<32; k++){
        float2 yv = y2[k];
        z += plo(w1p[k])*yv.x + phi(w1p[k])*yv.y;
      }
      float s = 1.f/(1.f+__expf(-z));
      sH1[t]  = 0.909f*z*s;
      sDp1[t] = 0.909f*s*(1.f + z*(1.f-s));
    }
    __syncthreads();
    // ph2: z2 = W2@h1 + b2
    if (t < WID){
      float z = sB2[t];
      const float2* hh = (const float2*)sH1;
      #pragma unroll 8
      for (int cp=0; cp<64; cp++){
        u32 u = sW2p[cp*128 + t];
        float2 hv = hh[cp];
        z += plo(u)*hv.x + phi(u)*hv.y;
      }
      float s = 1.f/(1.f+__expf(-z));
      sH2[t]  = 0.909f*z*s;
      sDp2[t] = 0.909f*s*(1.f + z*(1.f-s));
    }
    __syncthreads();
    // ph3: f = tanh(W3@h2 + b3), 16-lane split dot + shfl reduce
    {
      int l = t & 15, g = t >> 4;
      float h[8];
      #pragma unroll
      for (int cc=0; cc<8; cc++) h[cc] = sH2[8*l + cc];
      #pragma unroll 4
      for (int s8=0; s8<32; s8++){
        int row = s8*16 + g;
        float w8[8]; w3chunk(W3g, row, l, isbf, w8);
        float z = w8[0]*h[0]+w8[1]*h[1]+w8[2]*h[2]+w8[3]*h[3]
                + w8[4]*h[4]+w8[5]*h[5]+w8[6]*h[6]+w8[7]*h[7];
        z += __shfl_xor(z, 1); z += __shfl_xor(z, 2);
        z += __shfl_xor(z, 4); z += __shfl_xor(z, 8);
        if (l == 0) sF[row] = tanh_fast(z + sB3[row]);
      }
    }
    __syncthreads();
    // U-fold: u_j = sum_i C[j,i] f[i,:]  (JVP linear in direction)
    {
      int bb = t & 63, j0 = t >> 6;
      float u0=0.f, u1=0.f;
      #pragma unroll
      for (int i=0; i<8; i++){
        float fv = sF[i*64 + bb];
        u0 += sC[j0*8 + i]*fv;
        u1 += sC[(j0+4)*8 + i]*fv;
      }
      sU[j0*64 + bb]     = u0;
      sU[(j0+4)*64 + bb] = u1;
    }
    __syncthreads();
    // ph4: D1 = lipswish'(z1) * (W1 @ U^T), 8 dirs. r=t&127, 4 dirs each.
    {
      int r = t & 127, dg = (t >> 7) * 4;
      float a0=0.f, a1=0.f, a2=0.f, a3=0.f;
      const float4* u4 = (const float4*)sU;
      #pragma unroll
      for (int q=0; q<16; q++){
        u32 u0 = w1p[2*q], u1 = w1p[2*q+1];
        float wl0=plo(u0), wh0=phi(u0), wl1=plo(u1), wh1=phi(u1);
        float4 v0 = u4[(dg+0)*16 + q];
        float4 v1 = u4[(dg+1)*16 + q];
        float4 v2 = u4[(dg+2)*16 + q];
        float4 v3 = u4[(dg+3)*16 + q];
        a0 += wl0*v0.x + wh0*v0.y + wl1*v0.z + wh1*v0.w;
        a1 += wl0*v1.x + wh0*v1.y + wl1*v1.z + wh1*v1.w;
        a2 += wl0*v2.x + wh0*v2.y + wl1*v2.z + wh1*v2.w;
        a3 += wl0*v3.x + wh0*v3.y + wl1*v3.z + wh1*v3.w;
      }
      float dp = sDp1[r];
      float4 o; o.x=dp*a0; o.y=dp*a1; o.z=dp*a2; o.w=dp*a3;
      ((float4*)sD1)[r*2 + (t>>7)] = o;
    }
    __syncthreads();
    // ph5: D2 = lipswish'(z2) * (W2 @ D1), write transposed [dir][row]
    {
      int r = t & 127, dq = t >> 7;
      float a0=0.f, a1=0.f, a2=0.f, a3=0.f;
      const float4* d14 = (const float4*)sD1;
      #pragma unroll 8
      for (int cp=0; cp<64; cp++){
        u32 u = sW2p[cp*128 + r];
        float wl = plo(u), wh = phi(u);
        float4 va = d14[(2*cp+0)*2 + dq];
        float4 vb = d14[(2*cp+1)*2 + dq];
        a0 += wl*va.x + wh*vb.x;
        a1 += wl*va.y + wh*vb.y;
        a2 += wl*va.z + wh*vb.z;
        a3 += wl*va.w + wh*vb.w;
      }
      float dp = sDp2[r];
      sD2T[(4*dq+0)*128 + r] = dp*a0;
      sD2T[(4*dq+1)*128 + r] = dp*a1;
      sD2T[(4*dq+2)*128 + r] = dp*a2;
      sD2T[(4*dq+3)*128 + r] = dp*a3;
    }
    __syncthreads();
    // ph6: row r of block j only needs dir j: T3[r] = W3[r] . D2T[j]
    {
      int l = t & 15, g = t >> 4;
      #pragma unroll
      for (int j=0; j<8; j++){
        float d[8];
        #pragma unroll
        for (int cc=0; cc<8; cc++) d[cc] = sD2T[j*128 + 8*l + cc];
        #pragma unroll
        for (int ss=0; ss<4; ss++){
          int row = (j*4+ss)*16 + g;
          float w8[8]; w3chunk(W3g, row, l, isbf, w8);
          float z = w8[0]*d[0]+w8[1]*d[1]+w8[2]*d[2]+w8[3]*d[3]
                  + w8[4]*d[4]+w8[5]*d[5]+w8[6]*d[6]+w8[7]*d[7];
          z += __shfl_xor(z, 1); z += __shfl_xor(z, 2);
          z += __shfl_xor(z, 4); z += __shfl_xor(z, 8);
          if (l == 0){
            float fv = sF[row];
            sCon[row] = gcur[j]*fv + (1.f - fv*fv)*z;
          }
        }
      }
    }
    __syncthreads();
    // ph7: k[a] = sum_j contrib[j*64+a]
    if (t < HID){
      float k = 0.f;
      #pragma unroll
      for (int j=0; j<8; j++) k += sCon[j*64 + t];
      kout[t] = k;
    }
  };

  // ---- main scan over windows ----
  for (int s = 0; s < NWIN; s++){
    gcur = &sG[s*LSIG];
    // signed bracket-coefficient matrix C[j*8+i] from this window's logsig
    if (t < 64){
      int j = t >> 3, i = t & 7;
      float v = 0.f;
      if (i < j)      v =  gcur[8 + (7*i - (i*(i-1))/2 + (j-i-1))];
      else if (i > j) v = -gcur[8 + (7*j - (j*(j-1))/2 + (i-j-1))];
      sC[t] = v;
    }
    EVAL(sY, sK1);
    __syncthreads();
    if (t < HID) sYm[t] = sY[t] + sK1[t];
    EVAL(sYm, sK2);
    __syncthreads();
    if (t < HID) sY[t] = sY[t] + 0.5f*(sK1[t] + sK2[t]);
    __syncthreads();
    if (t < NOUT){
      float z = sBr[t] + sShift;
      #pragma unroll 8
      for (int a=0; a<64; a++) z += sWr[t*64+a]*sY[a];
      int idx = (b*33 + s + 1)*4 + t;
      if (isbf) ((u16*)outp)[idx] = f2bf(z); else ((float*)outp)[idx] = z;
    }
  }
}

extern "C" void kernel_launch(void* const* d_in, const int* in_sizes, int n_in,
                              void* d_out, int out_size, void* d_ws, size_t ws_size,
                              hipStream_t stream) {
  cde_kernel<<<dim3(NBATCH), dim3(256), 0, stream>>>(
      d_in[0],
      d_in[1],  d_in[2],
      d_in[3],  d_in[4],
      d_in[5],  d_in[6],
      d_in[7],  d_in[8],
      d_in[9],  d_in[10],
      d_in[11], d_in[12],
      d_in[13],
      d_out);
}

// Round 4
// 875.594 us; speedup vs baseline: 2.1473x; 2.1473x over previous
//
#include <hip/hip_runtime.h>

// log-ODE Neural CDE. B=32 chains, 32 windows, Heun step = 2 vector-field
// evals per window. fp32 in/out (verified R3), fp32 internal, bf16-packed
// weights for hot loops. One 256-thread block per batch element; only 32
// blocks -> 1 block/CU guaranteed, so LDS (154 KB) and VGPRs (~250) are free.
#define NBATCH 32
#define LPATH  513
#define DIM    8
#define HID    64
#define WLEN   16
#define NWIN   32
#define NOUT   4
#define WID    128
#define LSIG   36

typedef unsigned int u32;
typedef unsigned short u16;

__device__ __forceinline__ float plo(u32 u){ return __uint_as_float(u<<16); }
__device__ __forceinline__ float phi(u32 u){ return __uint_as_float(u & 0xffff0000u); }
__device__ __forceinline__ u16 f2bf(float f){
  u32 u = __float_as_uint(f);
  u32 r = (u + 0x7fffu + ((u>>16)&1u)) >> 16;
  return (u16)r;
}
__device__ __forceinline__ u32 pack2(float a, float b){
  return (u32)f2bf(a) | ((u32)f2bf(b) << 16);
}
__device__ __forceinline__ float tanh_fast(float x){
  float e = __expf(2.f*x);
  return 1.f - 2.f/(e+1.f);   // saturates to +/-1, no NaN for finite x
}
__device__ __forceinline__ void load8f(const float* p, int i8, float* o){
  const float4 a = ((const float4*)p)[2*i8];
  const float4 b = ((const float4*)p)[2*i8+1];
  o[0]=a.x; o[1]=a.y; o[2]=a.z; o[3]=a.w;
  o[4]=b.x; o[5]=b.y; o[6]=b.z; o[7]=b.w;
}

extern "C" __global__ __launch_bounds__(256, 1)
void cde_kernel(const float* __restrict__ cv,
                const float* __restrict__ Wi1g, const float* __restrict__ bi1g,
                const float* __restrict__ Wi2g, const float* __restrict__ bi2g,
                const float* __restrict__ W1g,  const float* __restrict__ b1g,
                const float* __restrict__ W2g,  const float* __restrict__ b2g,
                const float* __restrict__ W3g,  const float* __restrict__ b3g,
                const float* __restrict__ Wrg,  const float* __restrict__ brg,
                const float* __restrict__ shg,
                float* __restrict__ outp)
{
  // ---- LDS (~154 KB of the 160 KB addressable on gfx950) ----
  // W3 bf16 col-pairs, grouped 4 pairs/uint4: uint4 idx q*512+r = row r,
  // cols 8q..8q+7. Read with conflict-free lane-consecutive ds_read_b128.
  __shared__ __align__(16) u32 sW3v[32768];      // 128 KB
  __shared__ float sG[NWIN*LSIG];                // window log-signatures
  __shared__ __align__(16) float sF [512];       // f = tanh(W3 h2 + b3)
  __shared__ float sCon[512];                    // per-row contributions
  __shared__ __align__(16) float sD1[WID*8];     // [row][dir]
  __shared__ __align__(16) float sD2T[8*WID];    // [dir][row]
  __shared__ __align__(16) float sU [8*HID];     // folded JVP dirs [j][b]
  __shared__ __align__(16) float sH1[WID];
  __shared__ __align__(16) float sH2[WID];
  __shared__ float sDp1[WID], sDp2[WID];
  __shared__ __align__(16) float sY [HID];
  __shared__ __align__(16) float sYm[HID];
  __shared__ float sK1[HID], sK2[HID];
  __shared__ float sB1[WID], sB2[WID], sB3[512];
  __shared__ float sC[64];                       // bracket coeffs C[j*8+i]
  __shared__ float sWr[NOUT*HID];
  __shared__ float sBr[NOUT];
  __shared__ float sShift;
  __shared__ float sLw[HID];

  const int t = threadIdx.x;
  const int b = blockIdx.x;
  const uint4* sW3v4 = (const uint4*)sW3v;

  // ---- init: biases, readout weights ----
  if (t < WID){ sB1[t]=b1g[t]; sB2[t]=b2g[t]; }
  sB3[t]     = b3g[t];
  sB3[t+256] = b3g[t+256];
  sWr[t]     = Wrg[t];
  if (t < NOUT) sBr[t] = brg[t];
  if (t == 0)   sShift = shg[0];

  // ---- stage W3 into LDS as bf16 pairs (one-time) ----
  // wave: cp consecutive -> global float2 coalesced; LDS write 16-way
  // conflicted but one-time (~17k cyc total, negligible).
  for (int j = t; j < 32768; j += 256){
    int r = j >> 6, cp = j & 63;
    float2 f = ((const float2*)W3g)[r*64 + cp];
    sW3v[(cp>>2)*2048 + r*4 + (cp&3)] = pack2(f.x, f.y);
  }

  // ---- depth-2 Lyndon log-signatures, one window per thread (t<32) ----
  if (t < NWIN){
    const int base8 = b*LPATH + t*WLEN;
    float cur[8], pre[8], acc[8], lv[28];
    load8f(cv, base8, cur);
    #pragma unroll
    for (int d=0; d<8; d++){ pre[d]=0.f; acc[d]=0.f; }
    #pragma unroll
    for (int p=0; p<28; p++) lv[p]=0.f;
    for (int w=1; w<=WLEN; w++){
      float nxt[8], inc[8];
      load8f(cv, base8 + w, nxt);
      #pragma unroll
      for (int d=0; d<8; d++) inc[d] = nxt[d]-cur[d];
      int p=0;
      #pragma unroll
      for (int i=0; i<8; i++)
        #pragma unroll
        for (int j2=i+1; j2<8; j2++){ lv[p] += pre[i]*inc[j2] - pre[j2]*inc[i]; p++; }
      #pragma unroll
      for (int d=0; d<8; d++){ acc[d]+=inc[d]; pre[d]+=inc[d]; cur[d]=nxt[d]; }
    }
    float* gd = &sG[t*LSIG];
    #pragma unroll
    for (int d=0; d<8; d++) gd[d] = acc[d];
    #pragma unroll
    for (int p=0; p<28; p++) gd[8+p] = 0.5f*lv[p];
  }

  // ---- y0 = Wi2 @ lipswish(Wi1 @ x0 + bi1) + bi2 ----
  if (t < HID){
    float x0[8];
    load8f(cv, b*LPATH, x0);
    float z = bi1g[t];
    #pragma unroll
    for (int d=0; d<8; d++) z += Wi1g[t*8+d] * x0[d];
    float s = 1.f/(1.f+__expf(-z));
    sLw[t] = 0.909f*z*s;
  }
  __syncthreads();
  if (t < HID){
    float z = bi2g[t];
    #pragma unroll 8
    for (int k=0; k<64; k++) z += Wi2g[t*64+k] * sLw[k];
    sY[t] = z;
  }
  __syncthreads();
  if (t < NOUT){
    float z = sBr[t] + sShift;
    #pragma unroll 8
    for (int a=0; a<64; a++) z += sWr[t*64+a]*sY[a];
    outp[(b*33 + 0)*4 + t] = z;
  }

  // ---- per-thread weight registers: W1 row + W2 row (row t&127) ----
  u32 w1p[32], w2p[64];
  {
    int rw = t & 127;
    const float2* W1f = (const float2*)W1g;
    const float2* W2f = (const float2*)W2g;
    #pragma unroll
    for (int k=0; k<32; k++){ float2 f = W1f[rw*32 + k]; w1p[k] = pack2(f.x, f.y); }
    #pragma unroll
    for (int k=0; k<64; k++){ float2 f = W2f[rw*64 + k]; w2p[k] = pack2(f.x, f.y); }
  }

  const float* gcur = sG;

  // One vector-field eval: yin -> kout (= M(y) @ logsig; dt cancels)
  auto EVAL = [&](const float* yin, float* kout){
    __syncthreads();                              // yin, sC ready
    // ph1: z1 = W1@y + b1 ; h1 = lipswish, Dp1 = lipswish'
    if (t < WID){
      float z = sB1[t];
      const float2* y2 = (const float2*)yin;      // broadcast reads
      #pragma unroll
      for (int k=0; k<32; k++){
        float2 yv = y2[k];
        z += plo(w1p[k])*yv.x + phi(w1p[k])*yv.y;
      }
      float s = 1.f/(1.f+__expf(-z));
      sH1[t]  = 0.909f*z*s;
      sDp1[t] = 0.909f*s*(1.f + z*(1.f-s));
    }
    __syncthreads();
    // ph2: z2 = W2@h1 + b2 (W2 row in regs, h1 broadcast)
    if (t < WID){
      float z = sB2[t];
      const float2* hh = (const float2*)sH1;
      #pragma unroll
      for (int cp=0; cp<64; cp++){
        float2 hv = hh[cp];
        z += plo(w2p[cp])*hv.x + phi(w2p[cp])*hv.y;
      }
      float s = 1.f/(1.f+__expf(-z));
      sH2[t]  = 0.909f*z*s;
      sDp2[t] = 0.909f*s*(1.f + z*(1.f-s));
    }
    __syncthreads();
    // ph3: f = tanh(W3@h2 + b3). 2 rows/thread, LDS W3 b128 conflict-free,
    // h2 broadcast. No shuffles.
    float fr0, fr1;
    {
      const int r0 = t, r1 = t + 256;
      float z0 = sB3[r0], z1 = sB3[r1];
      const float4* h4 = (const float4*)sH2;
      #pragma unroll 4
      for (int q=0; q<16; q++){
        uint4 wa = sW3v4[q*512 + r0];
        uint4 wb = sW3v4[q*512 + r1];
        float4 hA = h4[2*q+0], hB = h4[2*q+1];
        z0 += plo(wa.x)*hA.x + phi(wa.x)*hA.y + plo(wa.y)*hA.z + phi(wa.y)*hA.w
            + plo(wa.z)*hB.x + phi(wa.z)*hB.y + plo(wa.w)*hB.z + phi(wa.w)*hB.w;
        z1 += plo(wb.x)*hA.x + phi(wb.x)*hA.y + plo(wb.y)*hA.z + phi(wb.y)*hA.w
            + plo(wb.z)*hB.x + phi(wb.z)*hB.y + plo(wb.w)*hB.z + phi(wb.w)*hB.w;
      }
      fr0 = tanh_fast(z0); fr1 = tanh_fast(z1);
      sF[r0] = fr0; sF[r1] = fr1;
    }
    __syncthreads();
    // U-fold: u_j = sum_i C[j,i] f[i,:]  (JVP linear in direction)
    {
      int bb = t & 63, j0 = t >> 6;
      float u0=0.f, u1=0.f;
      #pragma unroll
      for (int i=0; i<8; i++){
        float fv = sF[i*64 + bb];
        u0 += sC[j0*8 + i]*fv;
        u1 += sC[(j0+4)*8 + i]*fv;
      }
      sU[j0*64 + bb]     = u0;
      sU[(j0+4)*64 + bb] = u1;
    }
    __syncthreads();
    // ph4: D1 = lipswish'(z1) * (W1 @ U^T). r=t&127, 4 dirs each half.
    {
      int r = t & 127, dg = (t >> 7) * 4;
      float a0=0.f, a1=0.f, a2=0.f, a3=0.f;
      const float4* u4 = (const float4*)sU;       // broadcast reads
      #pragma unroll
      for (int q=0; q<16; q++){
        u32 u0 = w1p[2*q], u1 = w1p[2*q+1];
        float wl0=plo(u0), wh0=phi(u0), wl1=plo(u1), wh1=phi(u1);
        float4 v0 = u4[(dg+0)*16 + q];
        float4 v1 = u4[(dg+1)*16 + q];
        float4 v2 = u4[(dg+2)*16 + q];
        float4 v3 = u4[(dg+3)*16 + q];
        a0 += wl0*v0.x + wh0*v0.y + wl1*v0.z + wh1*v0.w;
        a1 += wl0*v1.x + wh0*v1.y + wl1*v1.z + wh1*v1.w;
        a2 += wl0*v2.x + wh0*v2.y + wl1*v2.z + wh1*v2.w;
        a3 += wl0*v3.x + wh0*v3.y + wl1*v3.z + wh1*v3.w;
      }
      float dp = sDp1[r];
      float4 o; o.x=dp*a0; o.y=dp*a1; o.z=dp*a2; o.w=dp*a3;
      ((float4*)sD1)[r*2 + (t>>7)] = o;
    }
    __syncthreads();
    // ph5: D2 = lipswish'(z2) * (W2 @ D1), write transposed [dir][row].
    // W2 row in regs; D1 reads are wave-uniform -> broadcast.
    {
      int r = t & 127, dq = t >> 7;
      float a0=0.f, a1=0.f, a2=0.f, a3=0.f;
      const float4* d14 = (const float4*)sD1;
      #pragma unroll
      for (int cp=0; cp<64; cp++){
        float wl = plo(w2p[cp]), wh = phi(w2p[cp]);
        float4 va = d14[(2*cp+0)*2 + dq];
        float4 vb = d14[(2*cp+1)*2 + dq];
        a0 += wl*va.x + wh*vb.x;
        a1 += wl*va.y + wh*vb.y;
        a2 += wl*va.z + wh*vb.z;
        a3 += wl*va.w + wh*vb.w;
      }
      float dp = sDp2[r];
      sD2T[(4*dq+0)*128 + r] = dp*a0;
      sD2T[(4*dq+1)*128 + r] = dp*a1;
      sD2T[(4*dq+2)*128 + r] = dp*a2;
      sD2T[(4*dq+3)*128 + r] = dp*a3;
    }
    __syncthreads();
    // ph6: T3[r] = W3[r] . D2T[j], j = r>>6. 2 rows/thread, no shuffles.
    {
      const int r0 = t, r1 = t + 256;
      const int j0 = t >> 6, j1 = j0 + 4;
      float a0 = 0.f, a1 = 0.f;
      const float4* d0 = (const float4*)&sD2T[j0*128];
      const float4* d1 = (const float4*)&sD2T[j1*128];
      #pragma unroll 4
      for (int q=0; q<16; q++){
        uint4 wa = sW3v4[q*512 + r0];
        uint4 wb = sW3v4[q*512 + r1];
        float4 xA = d0[2*q+0], xB = d0[2*q+1];
        float4 yA = d1[2*q+0], yB = d1[2*q+1];
        a0 += plo(wa.x)*xA.x + phi(wa.x)*xA.y + plo(wa.y)*xA.z + phi(wa.y)*xA.w
            + plo(wa.z)*xB.x + phi(wa.z)*xB.y + plo(wa.w)*xB.z + phi(wa.w)*xB.w;
        a1 += plo(wb.x)*yA.x + phi(wb.x)*yA.y + plo(wb.y)*yA.z + phi(wb.y)*yA.w
            + plo(wb.z)*yB.x + phi(wb.z)*yB.y + plo(wb.w)*yB.z + phi(wb.w)*yB.w;
      }
      sCon[r0] = gcur[j0]*fr0 + (1.f - fr0*fr0)*a0;
      sCon[r1] = gcur[j1]*fr1 + (1.f - fr1*fr1)*a1;
    }
    __syncthreads();
    // ph7: k[a] = sum_j contrib[j*64+a]
    if (t < HID){
      float k = 0.f;
      #pragma unroll
      for (int j=0; j<8; j++) k += sCon[j*64 + t];
      kout[t] = k;
    }
  };

  // ---- main scan over windows ----
  for (int s = 0; s < NWIN; s++){
    gcur = &sG[s*LSIG];
    // signed bracket-coefficient matrix C[j*8+i] from this window's logsig
    if (t < 64){
      int j = t >> 3, i = t & 7;
      float v = 0.f;
      if (i < j)      v =  gcur[8 + (7*i - (i*(i-1))/2 + (j-i-1))];
      else if (i > j) v = -gcur[8 + (7*j - (j*(j-1))/2 + (i-j-1))];
      sC[t] = v;
    }
    EVAL(sY, sK1);
    __syncthreads();
    if (t < HID) sYm[t] = sY[t] + sK1[t];
    EVAL(sYm, sK2);
    __syncthreads();
    if (t < HID) sY[t] = sY[t] + 0.5f*(sK1[t] + sK2[t]);
    __syncthreads();
    if (t < NOUT){
      float z = sBr[t] + sShift;
      #pragma unroll 8
      for (int a=0; a<64; a++) z += sWr[t*64+a]*sY[a];
      outp[(b*33 + s + 1)*4 + t] = z;
    }
  }
}

extern "C" void kernel_launch(void* const* d_in, const int* in_sizes, int n_in,
                              void* d_out, int out_size, void* d_ws, size_t ws_size,
                              hipStream_t stream) {
  cde_kernel<<<dim3(NBATCH), dim3(256), 0, stream>>>(
      (const float*)d_in[0],
      (const float*)d_in[1],  (const float*)d_in[2],
      (const float*)d_in[3],  (const float*)d_in[4],
      (const float*)d_in[5],  (const float*)d_in[6],
      (const float*)d_in[7],  (const float*)d_in[8],
      (const float*)d_in[9],  (const float*)d_in[10],
      (const float*)d_in[11], (const float*)d_in[12],
      (const float*)d_in[13],
      (float*)d_out);
}

// Round 6
// 356.299 us; speedup vs baseline: 5.2770x; 2.4575x over previous
//
#include <hip/hip_runtime.h>

// log-ODE Neural CDE. B=32 chains, 32 windows, Heun step = 2 vector-field
// evals per window. fp32 in/out, f32 accumulation, f16-packed weights and
// activations via v_dot2_f32_f16 (2 MAC/instr). 512 threads/block (8 waves,
// 2/SIMD for latency hiding), one block per batch element (32 blocks).
// W3 rows live in 64 VGPRs/thread -> no LDS traffic for the big matrix.
#define NBATCH 32
#define LPATH  513
#define NWIN   32
#define LSIG   36

typedef unsigned int u32;
typedef _Float16 h2 __attribute__((ext_vector_type(2)));

__device__ __forceinline__ u32 pkh(float a, float b){
  return __builtin_bit_cast(u32, __builtin_amdgcn_cvt_pkrtz(a, b)); // v_cvt_pkrtz_f16_f32
}
__device__ __forceinline__ float dot2(u32 a, u32 b, float c){
#if __has_builtin(__builtin_amdgcn_fdot2)
  return __builtin_amdgcn_fdot2(__builtin_bit_cast(h2,a),
                                __builtin_bit_cast(h2,b), c, false);
#else
  h2 x = __builtin_bit_cast(h2,a), y = __builtin_bit_cast(h2,b);
  return c + (float)x[0]*(float)y[0] + (float)x[1]*(float)y[1];
#endif
}
__device__ __forceinline__ float tanh_fast(float x){
  float e = __expf(2.f*x);
  return 1.f - 2.f/(e+1.f);
}

extern "C" __global__ __launch_bounds__(512, 2)
void cde_kernel(const float* __restrict__ cv,
                const float* __restrict__ Wi1g, const float* __restrict__ bi1g,
                const float* __restrict__ Wi2g, const float* __restrict__ bi2g,
                const float* __restrict__ W1g,  const float* __restrict__ b1g,
                const float* __restrict__ W2g,  const float* __restrict__ b2g,
                const float* __restrict__ W3g,  const float* __restrict__ b3g,
                const float* __restrict__ Wrg,  const float* __restrict__ brg,
                const float* __restrict__ shg,
                float* __restrict__ outp)
{
  // ---- LDS (~20 KB) ----
  __shared__ float sG[NWIN*LSIG];
  __shared__ __align__(16) float sF[512];      // tanh values (U-fold input)
  __shared__ float sCon[512];                  // per-row contributions
  __shared__ float sB3[512];
  __shared__ float sB1[128], sB2[128];
  __shared__ float sWr[256], sBr[4], sSh[1];
  __shared__ float sC[64];                     // bracket coeffs C[j*8+i]
  __shared__ float sY[64], sK1[64], sK2[64], sLw[64];
  __shared__ __align__(16) _Float16 sYinp[64];     // packed eval input
  __shared__ __align__(16) _Float16 sH1p[128];
  __shared__ __align__(16) _Float16 sH2p[128];
  __shared__ __align__(16) _Float16 sUp[8*64];     // [dir][b]
  __shared__ __align__(16) _Float16 sD1p[8*128];   // [dir][c]
  __shared__ __align__(16) _Float16 sD2p[8*128];   // [dir][c]

  const int t = threadIdx.x;          // 0..511
  const int b = blockIdx.x;
  const int r = t >> 2, c = t & 3;    // quad layout for ph1/2/4/5
  const int jw = t >> 6;              // wave index == dir block for ph3/6

  // ---- init biases / readout ----
  sB3[t] = b3g[t];
  if (t < 128){ sB1[t] = b1g[t]; sB2[t] = b2g[t]; }
  if (t < 256) sWr[t] = Wrg[t];
  if (t < 4)   sBr[t] = brg[t];
  if (t == 0)  sSh[0] = shg[0];

  // ---- one-time weight registers (f16 packed) ----
  u32 w3r[64];                         // W3 row t, cols 2m,2m+1 in w3r[m]
  {
    const float4* W3f4 = (const float4*)W3g;
    #pragma unroll
    for (int k=0; k<32; k++){
      float4 v = W3f4[t*32 + k];
      w3r[2*k]   = pkh(v.x, v.y);
      w3r[2*k+1] = pkh(v.z, v.w);
    }
  }
  u32 w1q[8];                          // W1 row r, cols 16c..16c+15
  {
    const float2* W1f2 = (const float2*)W1g;
    #pragma unroll
    for (int i=0; i<8; i++){
      float2 v = W1f2[r*32 + 8*c + i];
      w1q[i] = pkh(v.x, v.y);
    }
  }
  u32 w2q[16];                         // W2 row r, cols 32c..32c+31
  {
    const float2* W2f2 = (const float2*)W2g;
    #pragma unroll
    for (int i=0; i<16; i++){
      float2 v = W2f2[r*64 + 16*c + i];
      w2q[i] = pkh(v.x, v.y);
    }
  }

  // ---- depth-2 Lyndon log-signatures, one window per thread (t<32) ----
  if (t < NWIN){
    const float4* cv4 = (const float4*)cv;
    const int base = (b*LPATH + t*16)*2;      // float4 index of step 0
    float cur[8], pre[8], acc[8], lv[28];
    { float4 a = cv4[base], d = cv4[base+1];
      cur[0]=a.x;cur[1]=a.y;cur[2]=a.z;cur[3]=a.w;
      cur[4]=d.x;cur[5]=d.y;cur[6]=d.z;cur[7]=d.w; }
    #pragma unroll
    for (int d=0; d<8; d++){ pre[d]=0.f; acc[d]=0.f; }
    #pragma unroll
    for (int p=0; p<28; p++) lv[p]=0.f;
    for (int w=1; w<=16; w++){
      float nxt[8], inc[8];
      { float4 a = cv4[base+2*w], d = cv4[base+2*w+1];
        nxt[0]=a.x;nxt[1]=a.y;nxt[2]=a.z;nxt[3]=a.w;
        nxt[4]=d.x;nxt[5]=d.y;nxt[6]=d.z;nxt[7]=d.w; }
      #pragma unroll
      for (int d=0; d<8; d++) inc[d] = nxt[d]-cur[d];
      int p=0;
      #pragma unroll
      for (int i=0; i<8; i++)
        #pragma unroll
        for (int j2=i+1; j2<8; j2++){ lv[p] += pre[i]*inc[j2] - pre[j2]*inc[i]; p++; }
      #pragma unroll
      for (int d=0; d<8; d++){ acc[d]+=inc[d]; pre[d]+=inc[d]; cur[d]=nxt[d]; }
    }
    float* gd = &sG[t*LSIG];
    #pragma unroll
    for (int d=0; d<8; d++) gd[d] = acc[d];
    #pragma unroll
    for (int p=0; p<28; p++) gd[8+p] = 0.5f*lv[p];
  }

  // ---- y0 = Wi2 @ lipswish(Wi1 @ x0 + bi1) + bi2 ----
  if (t < 64){
    float z = bi1g[t];
    #pragma unroll
    for (int d=0; d<8; d++) z += Wi1g[t*8+d] * cv[(b*LPATH)*8 + d];
    float s = 1.f/(1.f+__expf(-z));
    sLw[t] = 0.909f*z*s;
  }
  __syncthreads();
  if (t < 64){
    float z = bi2g[t];
    #pragma unroll 8
    for (int k=0; k<64; k++) z += Wi2g[t*64+k] * sLw[k];
    sY[t] = z;
    sYinp[t] = (_Float16)z;
  }
  __syncthreads();
  if (t < 4){
    float z = sBr[t] + sSh[0];
    #pragma unroll 8
    for (int a=0; a<64; a++) z += sWr[t*64+a]*sY[a];
    outp[(b*33 + 0)*4 + t] = z;
  }

  // One vector-field eval: sYinp -> kout (= M(y) @ logsig; dt cancels)
  auto EVAL = [&](const float* gcur, float* kout){
    __syncthreads();                           // sYinp, sC ready
    float dp1, dp2;
    // ph1: z1 = W1@y + b1. quad(r,c): 16 cols each, xor-reduce.
    {
      const uint4* y4 = (const uint4*)sYinp;
      uint4 a = y4[2*c], d = y4[2*c+1];
      float z = dot2(w1q[0], a.x, 0.f);
      z = dot2(w1q[1], a.y, z); z = dot2(w1q[2], a.z, z); z = dot2(w1q[3], a.w, z);
      z = dot2(w1q[4], d.x, z); z = dot2(w1q[5], d.y, z);
      z = dot2(w1q[6], d.z, z); z = dot2(w1q[7], d.w, z);
      z += __shfl_xor(z, 1); z += __shfl_xor(z, 2);
      z += sB1[r];
      float s = 1.f/(1.f+__expf(-z));
      dp1 = 0.909f*s*(1.f + z*(1.f-s));
      if (c == 0) sH1p[r] = (_Float16)(0.909f*z*s);
    }
    __syncthreads();
    // ph2: z2 = W2@h1 + b2. quad(r,c): 32 cols each.
    {
      const uint4* h4 = (const uint4*)sH1p;
      uint4 a = h4[4*c], d = h4[4*c+1], e = h4[4*c+2], f = h4[4*c+3];
      float z = dot2(w2q[0], a.x, 0.f);
      z = dot2(w2q[1],  a.y, z); z = dot2(w2q[2],  a.z, z); z = dot2(w2q[3],  a.w, z);
      z = dot2(w2q[4],  d.x, z); z = dot2(w2q[5],  d.y, z); z = dot2(w2q[6],  d.z, z); z = dot2(w2q[7],  d.w, z);
      z = dot2(w2q[8],  e.x, z); z = dot2(w2q[9],  e.y, z); z = dot2(w2q[10], e.z, z); z = dot2(w2q[11], e.w, z);
      z = dot2(w2q[12], f.x, z); z = dot2(w2q[13], f.y, z); z = dot2(w2q[14], f.z, z); z = dot2(w2q[15], f.w, z);
      z += __shfl_xor(z, 1); z += __shfl_xor(z, 2);
      z += sB2[r];
      float s = 1.f/(1.f+__expf(-z));
      dp2 = 0.909f*s*(1.f + z*(1.f-s));
      if (c == 0) sH2p[r] = (_Float16)(0.909f*z*s);
    }
    __syncthreads();
    // ph3: f = tanh(W3@h2 + b3). 1 row/thread, W3 in regs, 4 acc chains.
    float fr;
    {
      const uint4* h4 = (const uint4*)sH2p;
      float a0=0.f, a1=0.f, a2=0.f, a3=0.f;
      #pragma unroll
      for (int q=0; q<16; q++){
        uint4 hv = h4[q];
        a0 = dot2(w3r[4*q+0], hv.x, a0);
        a1 = dot2(w3r[4*q+1], hv.y, a1);
        a2 = dot2(w3r[4*q+2], hv.z, a2);
        a3 = dot2(w3r[4*q+3], hv.w, a3);
      }
      fr = tanh_fast((a0+a1)+(a2+a3) + sB3[t]);
      sF[t] = fr;
    }
    __syncthreads();
    // U-fold: u_j[b] = sum_i C[j,i] f[i*64+b]; one entry per thread.
    {
      int bb = t & 63;
      float u = 0.f;
      #pragma unroll
      for (int i=0; i<8; i++) u += sC[jw*8 + i] * sF[i*64 + bb];
      sUp[jw*64 + bb] = (_Float16)u;
    }
    __syncthreads();
    // ph4: D1 = lipswish'(z1) * (W1 @ U^T). quad(r,c), 8 dirs.
    {
      const uint4* u4 = (const uint4*)sUp;
      float acc[8];
      #pragma unroll
      for (int dir=0; dir<8; dir++){
        uint4 a = u4[dir*8 + 2*c], d = u4[dir*8 + 2*c + 1];
        float z = dot2(w1q[0], a.x, 0.f);
        z = dot2(w1q[1], a.y, z); z = dot2(w1q[2], a.z, z); z = dot2(w1q[3], a.w, z);
        z = dot2(w1q[4], d.x, z); z = dot2(w1q[5], d.y, z);
        z = dot2(w1q[6], d.z, z); z = dot2(w1q[7], d.w, z);
        z += __shfl_xor(z, 1); z += __shfl_xor(z, 2);
        acc[dir] = z;
      }
      if (c == 0){
        #pragma unroll
        for (int dir=0; dir<8; dir++) sD1p[dir*128 + r] = (_Float16)(dp1*acc[dir]);
      }
    }
    __syncthreads();
    // ph5: D2 = lipswish'(z2) * (W2 @ D1). quad(r,c), 8 dirs.
    {
      const uint4* d4 = (const uint4*)sD1p;
      float acc[8];
      #pragma unroll
      for (int dir=0; dir<8; dir++){
        uint4 a = d4[dir*16 + 4*c], d = d4[dir*16 + 4*c + 1];
        uint4 e = d4[dir*16 + 4*c + 2], f = d4[dir*16 + 4*c + 3];
        float z = dot2(w2q[0], a.x, 0.f);
        z = dot2(w2q[1],  a.y, z); z = dot2(w2q[2],  a.z, z); z = dot2(w2q[3],  a.w, z);
        z = dot2(w2q[4],  d.x, z); z = dot2(w2q[5],  d.y, z); z = dot2(w2q[6],  d.z, z); z = dot2(w2q[7],  d.w, z);
        z = dot2(w2q[8],  e.x, z); z = dot2(w2q[9],  e.y, z); z = dot2(w2q[10], e.z, z); z = dot2(w2q[11], e.w, z);
        z = dot2(w2q[12], f.x, z); z = dot2(w2q[13], f.y, z); z = dot2(w2q[14], f.z, z); z = dot2(w2q[15], f.w, z);
        z += __shfl_xor(z, 1); z += __shfl_xor(z, 2);
        acc[dir] = z;
      }
      if (c == 0){
        #pragma unroll
        for (int dir=0; dir<8; dir++) sD2p[dir*128 + r] = (_Float16)(dp2*acc[dir]);
      }
    }
    __syncthreads();
    // ph6: T3[row] = W3[row] . D2[jw]; contribution. 1 row/thread, regs W3.
    {
      const uint4* d4 = (const uint4*)&sD2p[jw*128];
      float a0=0.f, a1=0.f, a2=0.f, a3=0.f;
      #pragma unroll
      for (int q=0; q<16; q++){
        uint4 dv = d4[q];
        a0 = dot2(w3r[4*q+0], dv.x, a0);
        a1 = dot2(w3r[4*q+1], dv.y, a1);
        a2 = dot2(w3r[4*q+2], dv.z, a2);
        a3 = dot2(w3r[4*q+3], dv.w, a3);
      }
      float t3 = (a0+a1)+(a2+a3);
      sCon[t] = gcur[jw]*fr + (1.f - fr*fr)*t3;
    }
    __syncthreads();
    // ph7: k[a] = sum_j contrib[j*64+a]
    if (t < 64){
      float k = 0.f;
      #pragma unroll
      for (int j=0; j<8; j++) k += sCon[j*64 + t];
      kout[t] = k;
    }
  };

  // ---- main scan over windows ----
  for (int s = 0; s < NWIN; s++){
    const float* gcur = &sG[s*LSIG];
    if (t < 64){                       // bracket coeff matrix C[j*8+i]
      int j = t >> 3, i = t & 7;
      float v = 0.f;
      if (i < j)      v =  gcur[8 + (7*i - (i*(i-1))/2 + (j-i-1))];
      else if (i > j) v = -gcur[8 + (7*j - (j*(j-1))/2 + (i-j-1))];
      sC[t] = v;
    }
    EVAL(gcur, sK1);
    __syncthreads();
    if (t < 64) sYinp[t] = (_Float16)(sY[t] + sK1[t]);
    EVAL(gcur, sK2);
    __syncthreads();
    if (t < 64){
      float yn = sY[t] + 0.5f*(sK1[t] + sK2[t]);
      sY[t] = yn;
      sYinp[t] = (_Float16)yn;
    }
    __syncthreads();
    if (t < 4){
      float z = sBr[t] + sSh[0];
      #pragma unroll 8
      for (int a=0; a<64; a++) z += sWr[t*64+a]*sY[a];
      outp[(b*33 + s + 1)*4 + t] = z;
    }
  }
}

extern "C" void kernel_launch(void* const* d_in, const int* in_sizes, int n_in,
                              void* d_out, int out_size, void* d_ws, size_t ws_size,
                              hipStream_t stream) {
  cde_kernel<<<dim3(NBATCH), dim3(512), 0, stream>>>(
      (const float*)d_in[0],
      (const float*)d_in[1],  (const float*)d_in[2],
      (const float*)d_in[3],  (const float*)d_in[4],
      (const float*)d_in[5],  (const float*)d_in[6],
      (const float*)d_in[7],  (const float*)d_in[8],
      (const float*)d_in[9],  (const float*)d_in[10],
      (const float*)d_in[11], (const float*)d_in[12],
      (const float*)d_in[13],
      (float*)d_out);
}